// Round 17
// baseline (26.915 us; speedup 1.0000x reference)
//
#include <hip/hip_runtime.h>

// Problem constants
#define B_IMG 8
#define C_IN  16
#define COUT  64
#define H0    36
#define H1    6
#define NB    6
#define NNODE 43
// OH=OW=16; output [8][64][16][16]

typedef float f32x2 __attribute__((ext_vector_type(2)));
typedef float f32x4 __attribute__((ext_vector_type(4)));

__device__ __forceinline__ float sigf(float v) { return 1.0f / (1.0f + __expf(-v)); }
__device__ __forceinline__ float4 sig4(float4 a) {
    return make_float4(sigf(a.x), sigf(a.y), sigf(a.z), sigf(a.w));
}

// 6-bit multilinear interp; delta-form table as f32x4 lo[8]|dd[8] in registers.
// g[0] contracts the MSB ... g[5] the LSB (matches reference einsum order).
__device__ __forceinline__ float lut_tree(const f32x4 lo[8], const f32x4 dd[8],
                                          const float g[NB]) {
    f32x4 v[8];
    const float g0 = g[0];
#pragma unroll
    for (int q = 0; q < 8; ++q) v[q] = lo[q] + dd[q] * g0;      // bit5 (MSB)
    const float g1 = g[1], g2 = g[2], g3 = g[3];
#pragma unroll
    for (int q = 0; q < 4; ++q) v[q] += (v[q + 4] - v[q]) * g1; // bit4
#pragma unroll
    for (int q = 0; q < 2; ++q) v[q] += (v[q + 2] - v[q]) * g2; // bit3
    v[0] += (v[1] - v[0]) * g3;                                 // bit2
    f32x2 a = {v[0].x, v[0].y};
    const f32x2 b = {v[0].z, v[0].w};
    a += (b - a) * g[4];                                        // bit1
    return a.x + (a.y - a.x) * g[5];                            // bit0
}

__device__ __forceinline__ void load_tbl(const float* tb, f32x4 lo[8], f32x4 dd[8]) {
    const f32x4* t4 = (const f32x4*)tb;
#pragma unroll
    for (int q = 0; q < 8; ++q) { lo[q] = t4[q]; dd[q] = t4[q + 8]; }
}

// Uniform-index select from 6 per-thread registers (idx is wave-uniform).
__device__ __forceinline__ float sel6(const float h0_, const float h1_, const float h2_,
                                      const float h3_, const float h4_, const float h5_,
                                      int s) {
    s = __builtin_amdgcn_readfirstlane(s);
    float r = h0_;
    r = (s == 1) ? h1_ : r;
    r = (s == 2) ? h2_ : r;
    r = (s == 3) ? h3_ : r;
    r = (s == 4) ? h4_ : r;
    r = (s == 5) ? h5_ : r;
    return r;
}

// Single fused kernel: block = (channel t, image img), 512 threads = 8 waves,
// 256 pixels. TWO barriers total (staging, post-A). Layers 1+2 fused
// per-thread with h1 in registers — no h1 LDS, no third barrier.
__global__ __launch_bounds__(512) void lutone_kernel(
    const float* __restrict__ x,
    const int*   __restrict__ idx0,
    const float* __restrict__ t0,
    const int*   __restrict__ idx1,
    const float* __restrict__ t1,
    const int*   __restrict__ idx2,
    const float* __restrict__ t2,
    float*       __restrict__ out)
{
    __shared__ float tblL[NNODE*64];   // sigmoid'd delta tables: lo[32]|dd[32]
    __shared__ float h0s[H0*256];      // [raw node][px] — bank = px, conflict-free
    __shared__ int   metaL[H0*NB*2];   // per (node,i): {off, rem}
    __shared__ int   idx1L[H1*NB];
    __shared__ int   idx2L[NB];

    const int tid  = threadIdx.x;
    const int w    = tid >> 6;
    const int lane = tid & 63;
    const int t    = blockIdx.x & 63;
    const int img  = blockIdx.x >> 6;

    // ---- stage sigmoid'd fp32 delta tables into LDS (344 items, 1 round) ----
    if (tid < NNODE*8) {
        const int node = tid >> 3, q = tid & 7;
        const float* src = (node < H0)      ? t0 + ((size_t)t*H0 + node)*64
                         : (node < H0+H1)   ? t1 + ((size_t)t*H1 + node - H0)*64
                                            : t2 + (size_t)t*64;
        const float4* s4 = (const float4*)src;
        const float4 lo = sig4(s4[q]);
        const float4 hi = sig4(s4[q + 8]);
        float4* tbl4 = (float4*)tblL;
        tbl4[node*16 + q]     = lo;
        tbl4[node*16 + 8 + q] = make_float4(hi.x - lo.x, hi.y - lo.y,
                                            hi.z - lo.z, hi.w - lo.w);
    }
    // ---- decode idx0 -> LDS meta (one thread per (node,bit)) ----
    if (tid < H0*NB) {
        const int raw = idx0[(size_t)t*(H0*NB) + tid];
        const int c2  = raw / 25;
        const int rem = raw - 25*c2;                   // kh*5 + kw
        const int kh  = rem / 5, kw = rem - 5*kh;
        metaL[tid*2 + 0] = c2*1024 + kh*32 + kw - 66;  // -(2*32+2) halo shift
        metaL[tid*2 + 1] = rem;
    }
    if (tid < H1*NB) idx1L[tid] = idx1[(size_t)t*(H1*NB) + tid];
    if (tid < NB)    idx2L[tid] = idx2[(size_t)t*NB + tid];

    // ---- wave-uniform used-node mask (scalar pipe, overlaps staging) ----
    const int* i1base = idx1 + t*(H1*NB);
    unsigned long long umask = 0ull;
#pragma unroll
    for (int j = 0; j < H1*NB; ++j) umask |= 1ull << i1base[j];

    // ---- per-lane pixel geometry (phase A: px = c*64 + lane) ----
    int base[4], vmask[4];
#pragma unroll
    for (int c = 0; c < 4; ++c) {
        const int p  = (c << 6) + lane;
        const int oh = p >> 4, ow = p & 15;
        base[c] = img*16384 + oh*64 + ow*2;            // oh2*32 + ow2
        const int hm = 0x1F ^ ((oh == 0) ? 0x03 : 0) ^ ((oh == 15) ? 0x10 : 0);
        const int wm = 0x1F ^ ((ow == 0) ? 0x03 : 0) ^ ((ow == 15) ? 0x10 : 0);
        int vm = 0;
#pragma unroll
        for (int kh = 0; kh < 5; ++kh)
            vm |= ((hm >> kh) & 1) ? (wm << (5*kh)) : 0;
        vmask[c] = vm;
    }

    // ---- this wave's node assignment (<=5 nodes, named regs: rule #20) ----
    int myn0 = -1, myn1 = -1, myn2 = -1, myn3 = -1, myn4 = -1;
    {
        int cnt = 0;
        for (int n = 0; n < H0; ++n) {
            if (!((umask >> n) & 1ull)) continue;
            const int slot = cnt++;
            if ((slot & 7) != w) continue;
            const int k = slot >> 3;
            if      (k == 0) myn0 = n;
            else if (k == 1) myn1 = n;
            else if (k == 2) myn2 = n;
            else if (k == 3) myn3 = n;
            else             myn4 = n;
        }
    }
    __syncthreads();   // tblL + metaL ready

    // ---- phase A: layer 0; table pinned in VGPRs across the 4 chunks ----
#define NODE_A(NN)                                                           \
    if ((NN) >= 0) {                                                         \
        const int4* mp = (const int4*)(metaL + (NN)*12);                     \
        const int4 ma = mp[0], mb = mp[1], mc = mp[2];                       \
        const int off_[NB] = {ma.x, ma.z, mb.x, mb.z, mc.x, mc.z};           \
        const int rem_[NB] = {ma.y, ma.w, mb.y, mb.w, mc.y, mc.w};           \
        f32x4 lo[8], dd[8];                                                  \
        load_tbl(tblL + (NN)*64, lo, dd);                                    \
        _Pragma("unroll")                                                    \
        for (int q = 0; q < 8; ++q)                                          \
            asm volatile("" : "+v"(lo[q]), "+v"(dd[q]));                     \
        _Pragma("unroll")                                                    \
        for (int c = 0; c < 4; ++c) {                                        \
            float g[NB];                                                     \
            _Pragma("unroll")                                                \
            for (int i = 0; i < NB; ++i) {                                   \
                const bool ok = ((vmask[c] >> rem_[i]) & 1) != 0;            \
                const float v = x[ok ? (base[c] + off_[i]) : 0];             \
                g[i] = ok ? v : 0.0f;                                        \
            }                                                                \
            h0s[(NN)*256 + (c << 6) + lane] = lut_tree(lo, dd, g);           \
        }                                                                    \
    }
    NODE_A(myn0)
    NODE_A(myn1)
    NODE_A(myn2)
    NODE_A(myn3)
    NODE_A(myn4)
#undef NODE_A
    __syncthreads();   // h0s ready — LAST barrier

    // ---- phases B+C fused: thread = pixel (waves 0..3); h1 in registers ----
    if (tid < 256) {
        float h1v0, h1v1, h1v2, h1v3, h1v4, h1v5;
#define NODE_B(N, DST)                                                       \
        {                                                                    \
            f32x4 lo[8], dd[8];                                              \
            load_tbl(tblL + (H0 + (N))*64, lo, dd);                          \
            const int* i1 = idx1L + (N)*NB;                                  \
            float g[NB];                                                     \
            _Pragma("unroll")                                                \
            for (int i = 0; i < NB; ++i) g[i] = h0s[i1[i]*256 + tid];        \
            DST = lut_tree(lo, dd, g);                                       \
        }
        NODE_B(0, h1v0)
        NODE_B(1, h1v1)
        NODE_B(2, h1v2)
        NODE_B(3, h1v3)
        NODE_B(4, h1v4)
        NODE_B(5, h1v5)
#undef NODE_B
        // layer 2: gathers via uniform-index register selects
        f32x4 lo[8], dd[8];
        load_tbl(tblL + (H0 + H1)*64, lo, dd);
        float g[NB];
#pragma unroll
        for (int i = 0; i < NB; ++i)
            g[i] = sel6(h1v0, h1v1, h1v2, h1v3, h1v4, h1v5, idx2L[i]);
        out[((size_t)img*COUT + t)*256 + tid] = lut_tree(lo, dd, g);
    }
}

extern "C" void kernel_launch(void* const* d_in, const int* in_sizes, int n_in,
                              void* d_out, int out_size, void* d_ws, size_t ws_size,
                              hipStream_t stream) {
    const float* x      = (const float*)d_in[0];
    const int*   idx0   = (const int*)  d_in[1];
    const float* table0 = (const float*)d_in[2];
    const int*   idx1   = (const int*)  d_in[3];
    const float* table1 = (const float*)d_in[4];
    const int*   idx2   = (const int*)  d_in[5];
    const float* table2 = (const float*)d_in[6];
    float* out = (float*)d_out;

    lutone_kernel<<<COUT * B_IMG, 512, 0, stream>>>(
        x, idx0, table0, idx1, table1, idx2, table2, out);
}

// Round 18
// 21.601 us; speedup vs baseline: 1.2460x; 1.2460x over previous
//
#include <hip/hip_runtime.h>

// Problem constants
#define B_IMG 8
#define C_IN  16
#define COUT  64
#define H0    36
#define H1    6
#define NB    6
#define NNODE 43
// OH=OW=16; output [8][64][16][16]

typedef float f32x2 __attribute__((ext_vector_type(2)));

__device__ __forceinline__ float sigf(float v) { return 1.0f / (1.0f + __expf(-v)); }

// 6-bit multilinear interp, delta-form table in registers.
// g[0] contracts the MSB ... g[5] the LSB (matches reference einsum order).
__device__ __forceinline__ float lut_contract_reg(const float4 lo4[8], const float4 dd4[8],
                                                  const float g[NB]) {
    f32x2 v[16];
    const float g0 = g[0];
#pragma unroll
    for (int q = 0; q < 8; ++q) {
        v[2*q+0] = (f32x2){lo4[q].x, lo4[q].y} + (f32x2){dd4[q].x, dd4[q].y} * g0;
        v[2*q+1] = (f32x2){lo4[q].z, lo4[q].w} + (f32x2){dd4[q].z, dd4[q].w} * g0;
    }
#pragma unroll
    for (int i = 1; i < 5; ++i) {
        const int vh = 16 >> i;
        const float gi = g[i];
#pragma unroll
        for (int r = 0; r < vh; ++r)
            v[r] += (v[r + vh] - v[r]) * gi;
    }
    return v[0].x + (v[0].y - v[0].x) * g[5];
}

// Read a 64-entry delta table from LDS (wave-uniform addr -> broadcast reads).
__device__ __forceinline__ void load_tbl_lds(const float* tb, float4 lo4[8], float4 dd4[8]) {
    const float4* t4 = (const float4*)tb;
#pragma unroll
    for (int q = 0; q < 8; ++q) { lo4[q] = t4[q]; dd4[q] = t4[q + 8]; }
}

// Single fused kernel: block = (channel t, image img), 512 threads = 8 waves,
// 256 pixels. Per-channel setup (sigmoid tables, idx0 decode) staged in LDS.
__global__ __launch_bounds__(512) void lutone_kernel(
    const float* __restrict__ x,
    const int*   __restrict__ idx0,
    const float* __restrict__ t0,
    const int*   __restrict__ idx1,
    const float* __restrict__ t1,
    const int*   __restrict__ idx2,
    const float* __restrict__ t2,
    float*       __restrict__ out)
{
    __shared__ float tblL[NNODE*64];   // sigmoid'd delta tables: lo[32]|dd[32]
    __shared__ float h0s[H0*256];      // [raw node][px] — bank = px, conflict-free
    __shared__ float h1s[H1*256];
    __shared__ int   metaL[H0*NB*2];   // per (node,i): {off, rem}

    const int tid  = threadIdx.x;
    const int w    = tid >> 6;
    const int lane = tid & 63;
    const int t    = blockIdx.x & 63;
    const int img  = blockIdx.x >> 6;

    // ---- stage sigmoid'd delta tables into LDS ----
    for (int e = tid; e < NNODE*32; e += 512) {
        const int node = e >> 5, k = e & 31;
        const float* src = (node < H0)      ? t0 + ((size_t)t*H0 + node)*64
                         : (node < H0+H1)   ? t1 + ((size_t)t*H1 + node - H0)*64
                                            : t2 + (size_t)t*64;
        const float lo = sigf(src[k]);
        const float hi = sigf(src[k + 32]);
        tblL[node*64 + k]      = lo;
        tblL[node*64 + 32 + k] = hi - lo;
    }
    // ---- decode idx0 -> LDS meta (one thread per (node,bit)) ----
    if (tid < H0*NB) {
        const int raw = idx0[(size_t)t*(H0*NB) + tid];
        const int c2  = raw / 25;
        const int rem = raw - 25*c2;                 // kh*5 + kw
        const int kh  = rem / 5, kw = rem - 5*kh;
        metaL[tid*2 + 0] = c2*1024 + kh*32 + kw - 66;  // -(2*32+2) halo shift
        metaL[tid*2 + 1] = rem;
    }

    // ---- wave-uniform used-node mask (scalar pipe, overlaps staging) ----
    const int* i1base = idx1 + t*(H1*NB);
    unsigned long long umask = 0ull;
#pragma unroll
    for (int j = 0; j < H1*NB; ++j) umask |= 1ull << i1base[j];

    // ---- per-lane pixel geometry: base addr + 25-bit (kh,kw) validity mask ----
    int base[4], vmask[4];
#pragma unroll
    for (int c = 0; c < 4; ++c) {
        const int p  = (c << 6) + lane;
        const int oh = p >> 4, ow = p & 15;
        base[c] = img*16384 + oh*64 + ow*2;            // oh2*32 + ow2
        const int hm = 0x1F ^ ((oh == 0) ? 0x03 : 0) ^ ((oh == 15) ? 0x10 : 0);
        const int wm = 0x1F ^ ((ow == 0) ? 0x03 : 0) ^ ((ow == 15) ? 0x10 : 0);
        int vm = 0;
#pragma unroll
        for (int kh = 0; kh < 5; ++kh)
            vm |= ((hm >> kh) & 1) ? (wm << (5*kh)) : 0;
        vmask[c] = vm;
    }

    // ---- this wave's node assignment (<=5 nodes, named regs: rule #20) ----
    int myn0 = -1, myn1 = -1, myn2 = -1, myn3 = -1, myn4 = -1;
    {
        int cnt = 0;
        for (int n = 0; n < H0; ++n) {
            if (!((umask >> n) & 1ull)) continue;
            const int slot = cnt++;
            if ((slot & 7) != w) continue;
            const int k = slot >> 3;
            if      (k == 0) myn0 = n;
            else if (k == 1) myn1 = n;
            else if (k == 2) myn2 = n;
            else if (k == 3) myn3 = n;
            else             myn4 = n;
        }
    }
    __syncthreads();

    // ---- phase A: layer 0, straight-lined so the scheduler can pipeline ----
#define NODE_A(NN)                                                           \
    if ((NN) >= 0) {                                                         \
        const int4* mp = (const int4*)(metaL + (NN)*12);                     \
        const int4 ma = mp[0], mb = mp[1], mc = mp[2];                       \
        float4 lo4[8], dd4[8];                                               \
        load_tbl_lds(tblL + (NN)*64, lo4, dd4);                              \
        _Pragma("unroll")                                                    \
        for (int c = 0; c < 4; ++c) {                                        \
            const int off_[NB] = {ma.x, ma.z, mb.x, mb.z, mc.x, mc.z};       \
            const int rem_[NB] = {ma.y, ma.w, mb.y, mb.w, mc.y, mc.w};       \
            float g[NB];                                                     \
            _Pragma("unroll")                                                \
            for (int i = 0; i < NB; ++i) {                                   \
                const bool ok = ((vmask[c] >> rem_[i]) & 1) != 0;            \
                const float v = x[ok ? (base[c] + off_[i]) : 0];             \
                g[i] = ok ? v : 0.0f;                                        \
            }                                                                \
            h0s[(NN)*256 + (c << 6) + lane] = lut_contract_reg(lo4, dd4, g); \
        }                                                                    \
    }
    NODE_A(myn0)
    NODE_A(myn1)
    NODE_A(myn2)
    NODE_A(myn3)
    NODE_A(myn4)
#undef NODE_A
    __syncthreads();

    // ---- phase B: layer 1 on all 8 waves (24 chunk-units, <=3 per wave) ----
    if (w < H1) {
        // waves 0..5: own node w, chunks 0..2
        float4 lo4[8], dd4[8];
        load_tbl_lds(tblL + (H0 + w)*64, lo4, dd4);
        const int* i1 = idx1 + ((size_t)t*H1 + w)*NB;
        const int s0 = i1[0], s1 = i1[1], s2 = i1[2];
        const int s3 = i1[3], s4 = i1[4], s5 = i1[5];
#pragma unroll
        for (int c = 0; c < 3; ++c) {
            const int px = (c << 6) + lane;
            float g[NB];
            g[0] = h0s[s0*256 + px]; g[1] = h0s[s1*256 + px]; g[2] = h0s[s2*256 + px];
            g[3] = h0s[s3*256 + px]; g[4] = h0s[s4*256 + px]; g[5] = h0s[s5*256 + px];
            h1s[w*256 + px] = lut_contract_reg(lo4, dd4, g);
        }
    } else {
        // waves 6,7: chunk 3 of nodes 0..2 / 3..5
        const int nb0 = (w == 6) ? 0 : 3;
        const int px  = (3 << 6) + lane;
#pragma unroll
        for (int k = 0; k < 3; ++k) {
            const int n = nb0 + k;
            float4 lo4[8], dd4[8];
            load_tbl_lds(tblL + (H0 + n)*64, lo4, dd4);
            const int* i1 = idx1 + ((size_t)t*H1 + n)*NB;
            float g[NB];
            g[0] = h0s[i1[0]*256 + px]; g[1] = h0s[i1[1]*256 + px];
            g[2] = h0s[i1[2]*256 + px]; g[3] = h0s[i1[3]*256 + px];
            g[4] = h0s[i1[4]*256 + px]; g[5] = h0s[i1[5]*256 + px];
            h1s[n*256 + px] = lut_contract_reg(lo4, dd4, g);
        }
    }
    __syncthreads();

    // ---- phase C: layer 2; waves 0..3 take one 64-px chunk each ----
    if (w < 4) {
        float4 lo4[8], dd4[8];
        load_tbl_lds(tblL + (H0 + H1)*64, lo4, dd4);
        const int* i2 = idx2 + (size_t)t*NB;
        const int px = (w << 6) + lane;
        float g[NB];
#pragma unroll
        for (int i = 0; i < NB; ++i) g[i] = h1s[i2[i]*256 + px];
        out[((size_t)img*COUT + t)*256 + px] = lut_contract_reg(lo4, dd4, g);
    }
}

extern "C" void kernel_launch(void* const* d_in, const int* in_sizes, int n_in,
                              void* d_out, int out_size, void* d_ws, size_t ws_size,
                              hipStream_t stream) {
    const float* x      = (const float*)d_in[0];
    const int*   idx0   = (const int*)  d_in[1];
    const float* table0 = (const float*)d_in[2];
    const int*   idx1   = (const int*)  d_in[3];
    const float* table1 = (const float*)d_in[4];
    const int*   idx2   = (const int*)  d_in[5];
    const float* table2 = (const float*)d_in[6];
    float* out = (float*)d_out;

    lutone_kernel<<<COUT * B_IMG, 512, 0, stream>>>(
        x, idx0, table0, idx1, table1, idx2, table2, out);
}